// Round 16
// baseline (327.683 us; speedup 1.0000x reference)
//
#include <hip/hip_runtime.h>
#include <hip/hip_bf16.h>
#include <stdint.h>

#define NN 8192
#define INF 128
#define OUTF 64
#define ALPHA 0.2f
#define RB 128      // rows per attn block
#define JB 1024     // j-range per attn block
#define JPH 128     // j per staged phase
#define NPH (JB / JPH)

typedef __attribute__((ext_vector_type(8))) short s16x8;
typedef __attribute__((ext_vector_type(4))) float f32x4;
typedef __attribute__((ext_vector_type(4))) int i32x4;

typedef __attribute__((address_space(1))) const void ga_cv;
typedef __attribute__((address_space(3))) void lds_v;

__device__ __forceinline__ unsigned short f2bf(float f) {
    union { float f; unsigned int u; } v; v.f = f;
    return (unsigned short)((v.u + 0x8000u) >> 16);   // round-half-up (validated R4-R14)
}
__device__ __forceinline__ float bits2f(unsigned int u) {
    union { unsigned int u; float f; } v; v.u = u;
    return v.f;
}

// Kernel 1: zero cnt + Wh = h@W -> Wh1 (f32), WhbT (bf16 [64][8192]),
// BP[j] = pack(bf16(e^Wh2_j), bf16(e^{0.2 Wh2_j}))
__global__ void prep_kernel(const float* __restrict__ h, const float* __restrict__ W,
                            const float* __restrict__ a,
                            float* __restrict__ Wh1,
                            unsigned short* __restrict__ WhbT,
                            unsigned int* __restrict__ BP,
                            int* __restrict__ cnt) {
    const int gid = blockIdx.x * 256 + threadIdx.x;
    if (gid < NN / RB) cnt[gid] = 0;

    __shared__ float ldsW[INF * OUTF];
    int t = threadIdx.x;
    for (int idx = t; idx < INF * OUTF; idx += 256) ldsW[idx] = W[idx];
    __syncthreads();
    int r = blockIdx.x * 4 + (t >> 6);
    int c = t & 63;
    const float4* h4 = reinterpret_cast<const float4*>(h + (size_t)r * INF);
    float dot = 0.f;
#pragma unroll
    for (int kk = 0; kk < INF / 4; ++kk) {
        float4 hv = h4[kk];
        dot += hv.x * ldsW[(4 * kk + 0) * OUTF + c];
        dot += hv.y * ldsW[(4 * kk + 1) * OUTF + c];
        dot += hv.z * ldsW[(4 * kk + 2) * OUTF + c];
        dot += hv.w * ldsW[(4 * kk + 3) * OUTF + c];
    }
    union { float f; unsigned int u; } vv; vv.f = dot;
    unsigned int rr = vv.u + 0x7fffu + ((vv.u >> 16) & 1u);
    WhbT[(size_t)c * NN + r] = (unsigned short)(rr >> 16);   // RNE
    float v1 = dot * a[c];
    float v2 = dot * a[OUTF + c];
#pragma unroll
    for (int off = 32; off >= 1; off >>= 1) {
        v1 += __shfl_xor(v1, off, 64);
        v2 += __shfl_xor(v2, off, 64);
    }
    if (c == 0) {
        Wh1[r] = v1;
        unsigned int lo = f2bf(__expf(v2));
        unsigned int hi = f2bf(__expf(ALPHA * v2));
        BP[r] = lo | (hi << 16);
    }
}

// Kernel 2: R13 pipeline + deterministic fused finalize. Sliced stores are
// unchanged (one writer per (q,row,col) -> bitwise deterministic); the last
// q-block per row-group sums the 8 slices in FIXED q order and writes out.
__launch_bounds__(512, 4)
__global__ void attn_kernel(const int* __restrict__ adj,
                            const float* __restrict__ Wh1,
                            const unsigned short* __restrict__ WhbT,
                            const unsigned int* __restrict__ BPg,
                            float* __restrict__ accS, float* __restrict__ sS,
                            int* __restrict__ cnt, float* __restrict__ out) {
    __shared__ unsigned short Bpanel[2][64 * JPH];   // 2 x 16 KB
    __shared__ unsigned int ldsBP[JB];               // 4 KB
    __shared__ int isLast;
    const int tid = threadIdx.x;
    const int w = tid >> 6;
    const int l = tid & 63;
    const int il = l & 15;
    const int ks = l >> 4;
    const int g = blockIdx.x >> 3;
    const int q = blockIdx.x & 7;      // j-group == XCD (round-robin)
    const int rowbase = g * RB + w * 16;
    const int i = rowbase + il;
    const int jbase = q * JB;

    const float wh1 = Wh1[i];
    const float A1 = __expf(wh1);
    const float A2 = __expf(ALPHA * wh1);

    // stage BP slice for this block's j-range (once)
    for (int idx = tid; idx < JB; idx += 512) ldsBP[idx] = BPg[jbase + idx];

#define STAGE(ph) { \
    unsigned short* dst0 = &Bpanel[(ph) & 1][w * 1024]; \
    _Pragma("unroll") \
    for (int k = 0; k < 2; ++k) { \
        int c = w * 8 + k * 4 + (l >> 4); \
        int jl = ((l & 15) * 8) ^ ((c & 7) * 8); \
        const unsigned short* src = WhbT + (size_t)c * NN + jbase + (ph) * JPH + jl; \
        __builtin_amdgcn_global_load_lds((ga_cv*)src, (lds_v*)(dst0 + k * 512), 16, 0, 0); \
    } }

#define ADJHALF(dst, ph, HALF) { \
    _Pragma("unroll") \
    for (int k = 0; k < 2; ++k) { \
        const int jo = (ph) * JPH + (2 * (HALF) + k) * 32 + ks * 8; \
        dst[2 * k]     = *reinterpret_cast<const i32x4*>(adj + adjRow + jbase + jo); \
        dst[2 * k + 1] = *reinterpret_cast<const i32x4*>(adj + adjRow + jbase + jo + 4); \
    } }

#define COMPUTE_HALF(ph, HALF, CUR) { \
    _Pragma("unroll") \
    for (int kk2 = 0; kk2 < 2; ++kk2) { \
        const int ks8 = 2 * (HALF) + kk2; \
        const int jo = (ph) * JPH + ks8 * 32 + ks * 8; \
        i32x4 p0 = *reinterpret_cast<const i32x4*>(&ldsBP[jo]); \
        i32x4 p1 = *reinterpret_cast<const i32x4*>(&ldsBP[jo + 4]); \
        int pv[8] = {p0.x, p0.y, p0.z, p0.w, p1.x, p1.y, p1.z, p1.w}; \
        int av[8] = {CUR[2 * kk2].x, CUR[2 * kk2].y, CUR[2 * kk2].z, CUR[2 * kk2].w, \
                     CUR[2 * kk2 + 1].x, CUR[2 * kk2 + 1].y, CUR[2 * kk2 + 1].z, CUR[2 * kk2 + 1].w}; \
        s16x8 afrag; \
        _Pragma("unroll") \
        for (int b = 0; b < 8; ++b) { \
            unsigned int u = (unsigned int)pv[b]; \
            float b1 = bits2f(u << 16); \
            float b2 = bits2f(u & 0xffff0000u); \
            float pf = fmaxf(A1 * b1, A2 * b2); \
            pf = av[b] ? pf : 0.f; \
            afrag[b] = (short)f2bf(pf); \
        } \
        acc_s = __builtin_amdgcn_mfma_f32_16x16x32_bf16(afrag, ones, acc_s, 0, 0, 0); \
        const int off_e = (ks8 * 32 + ks * 8) ^ swzmask; \
        _Pragma("unroll") \
        for (int ct = 0; ct < 4; ++ct) { \
            s16x8 bfrag = *reinterpret_cast<const s16x8*>( \
                &Bpanel[(ph) & 1][(ct * 16 + il) * JPH + off_e]); \
            acc[ct] = __builtin_amdgcn_mfma_f32_16x16x32_bf16(afrag, bfrag, acc[ct], 0, 0, 0); \
        } \
    } }

#define VMW(n) { asm volatile("s_waitcnt vmcnt(" #n ")" ::: "memory"); \
                 __builtin_amdgcn_sched_barrier(0); }

    f32x4 acc[4] = {{0,0,0,0},{0,0,0,0},{0,0,0,0},{0,0,0,0}};
    f32x4 acc_s = {0,0,0,0};
    s16x8 ones;
#pragma unroll
    for (int b = 0; b < 8; ++b) ones[b] = (short)0x3F80;  // bf16 1.0

    const size_t adjRow = (size_t)i * NN;
    const int swzmask = (il & 7) * 8;

    i32x4 G0[4], G1[4];

    // prologue: ldsBP fill + STAGE(0) retired; G0(0),G1(0) left in flight
    STAGE(0);
    __builtin_amdgcn_sched_barrier(0);
    ADJHALF(G0, 0, 0);
    ADJHALF(G1, 0, 1);
    __builtin_amdgcn_sched_barrier(0);
    asm volatile("s_waitcnt vmcnt(8) lgkmcnt(0)" ::: "memory");
    __builtin_amdgcn_s_barrier();
    __builtin_amdgcn_sched_barrier(0);

    // invariant at each phase entry: outstanding = [G0(ph) 4, G1(ph) 4]
    for (int ph = 0; ph < NPH - 1; ++ph) {
        STAGE(ph + 1);                     // -> [G0 4, G1 4, ST 2]
        __builtin_amdgcn_sched_barrier(0);
        VMW(6);                            // retire G0(ph)
        COMPUTE_HALF(ph, 0, G0);
        __builtin_amdgcn_sched_barrier(0);
        ADJHALF(G0, ph + 1, 0);            // -> [G1 4, ST 2, G0' 4]
        __builtin_amdgcn_sched_barrier(0);
        VMW(6);                            // retire G1(ph)
        COMPUTE_HALF(ph, 1, G1);
        __builtin_amdgcn_sched_barrier(0);
        ADJHALF(G1, ph + 1, 1);            // -> [ST 2, G0' 4, G1' 4]
        __builtin_amdgcn_sched_barrier(0);
        VMW(8);                            // retire ST; G0',G1' fly across barrier
        __builtin_amdgcn_s_barrier();
        __builtin_amdgcn_sched_barrier(0);
    }
    // peeled last phase
    VMW(4);
    COMPUTE_HALF(NPH - 1, 0, G0);
    VMW(0);
    COMPUTE_HALF(NPH - 1, 1, G1);

    // sliced stores: every (q,row,col) written exactly once (deterministic)
#pragma unroll
    for (int ct = 0; ct < 4; ++ct)
#pragma unroll
        for (int r = 0; r < 4; ++r)
            accS[((size_t)q * NN + rowbase + ks * 4 + r) * OUTF + ct * 16 + il] = acc[ct][r];
    if (il == 0) {
#pragma unroll
        for (int r = 0; r < 4; ++r)
            sS[q * NN + rowbase + ks * 4 + r] = acc_s[r];
    }

    // fused finalize: last q-block of this row-group sums slices in fixed order
    __threadfence();
    __syncthreads();
    if (tid == 0) {
        int old = __hip_atomic_fetch_add(&cnt[g], 1, __ATOMIC_ACQ_REL,
                                         __HIP_MEMORY_SCOPE_AGENT);
        isLast = (old == 7);
    }
    __syncthreads();
    if (isLast) {
        __threadfence();
        const int base = g * RB;   // 128 rows x 64 cols, 512 threads -> 16 each
        for (int idx = tid; idx < RB * OUTF; idx += 512) {
            const int row = idx >> 6, col = idx & 63;
            float ss = 0.f, v = 0.f;
#pragma unroll
            for (int qq = 0; qq < 8; ++qq) {   // FIXED order -> deterministic
                ss += __hip_atomic_load(&sS[qq * NN + base + row],
                                        __ATOMIC_RELAXED, __HIP_MEMORY_SCOPE_AGENT);
                v  += __hip_atomic_load(&accS[((size_t)qq * NN + base + row) * OUTF + col],
                                        __ATOMIC_RELAXED, __HIP_MEMORY_SCOPE_AGENT);
            }
            float qv = (ss > 0.f) ? v / ss : 0.f;
            out[(size_t)(base + row) * OUTF + col] = (qv > 0.f) ? qv : (__expf(qv) - 1.f);
        }
    }
}

extern "C" void kernel_launch(void* const* d_in, const int* in_sizes, int n_in,
                              void* d_out, int out_size, void* d_ws, size_t ws_size,
                              hipStream_t stream) {
    const float* h   = (const float*)d_in[0];
    const int*   adj = (const int*)d_in[1];
    const float* W   = (const float*)d_in[2];
    const float* a   = (const float*)d_in[3];
    float* out = (float*)d_out;

    char* ws = (char*)d_ws;
    float* Wh1        = (float*)(ws);                            // 32 KB
    unsigned int* BP  = (unsigned int*)(ws + 32 * 1024);         // 32 KB
    unsigned short* WhbT = (unsigned short*)(ws + 64 * 1024);    // 1 MB
    float* accS = (float*)(ws + 2 * 1024 * 1024);                // 8 x 2 MB = 16 MB
    float* sS   = (float*)(ws + 18 * 1024 * 1024);               // 8 x 32 KB
    int*   cnt  = (int*)(ws + 19 * 1024 * 1024);                 // 256 B

    hipLaunchKernelGGL(prep_kernel, dim3(NN / 4), dim3(256), 0, stream,
                       h, W, a, Wh1, WhbT, BP, cnt);
    hipLaunchKernelGGL(attn_kernel, dim3((NN / RB) * (NN / JB)), dim3(512), 0, stream,
                       adj, Wh1, WhbT, BP, accS, sS, cnt, out);
}

// Round 17
// 76.389 us; speedup vs baseline: 4.2897x; 4.2897x over previous
//
#include <hip/hip_runtime.h>
#include <hip/hip_bf16.h>
#include <stdint.h>

#define NN 8192
#define INF 128
#define OUTF 64
#define ALPHA 0.2f
#define RB 128      // rows per attn block
#define JB 1024     // j-range per attn block
#define JPH 128     // j per staged phase
#define NPH (JB / JPH)

typedef __attribute__((ext_vector_type(8))) short s16x8;
typedef __attribute__((ext_vector_type(4))) float f32x4;
typedef __attribute__((ext_vector_type(4))) int i32x4;

typedef __attribute__((address_space(1))) const void ga_cv;
typedef __attribute__((address_space(3))) void lds_v;

__device__ __forceinline__ unsigned short f2bf(float f) {
    union { float f; unsigned int u; } v; v.f = f;
    return (unsigned short)((v.u + 0x8000u) >> 16);   // round-half-up (validated R4-R13)
}
__device__ __forceinline__ float bits2f(unsigned int u) {
    union { unsigned int u; float f; } v; v.u = u;
    return v.f;
}

// Kernel 1: Wh = h@W -> Wh1 (f32), WhbT (bf16 [64][8192]),
// BP[j] = pack(bf16(e^Wh2_j), bf16(e^{0.2 Wh2_j}))
__global__ void prep_kernel(const float* __restrict__ h, const float* __restrict__ W,
                            const float* __restrict__ a,
                            float* __restrict__ Wh1,
                            unsigned short* __restrict__ WhbT,
                            unsigned int* __restrict__ BP) {
    __shared__ float ldsW[INF * OUTF];
    int t = threadIdx.x;
    for (int idx = t; idx < INF * OUTF; idx += 256) ldsW[idx] = W[idx];
    __syncthreads();
    int r = blockIdx.x * 4 + (t >> 6);
    int c = t & 63;
    const float4* h4 = reinterpret_cast<const float4*>(h + (size_t)r * INF);
    float dot = 0.f;
#pragma unroll
    for (int kk = 0; kk < INF / 4; ++kk) {
        float4 hv = h4[kk];
        dot += hv.x * ldsW[(4 * kk + 0) * OUTF + c];
        dot += hv.y * ldsW[(4 * kk + 1) * OUTF + c];
        dot += hv.z * ldsW[(4 * kk + 2) * OUTF + c];
        dot += hv.w * ldsW[(4 * kk + 3) * OUTF + c];
    }
    union { float f; unsigned int u; } vv; vv.f = dot;
    unsigned int rr = vv.u + 0x7fffu + ((vv.u >> 16) & 1u);
    WhbT[(size_t)c * NN + r] = (unsigned short)(rr >> 16);   // RNE
    float v1 = dot * a[c];
    float v2 = dot * a[OUTF + c];
#pragma unroll
    for (int off = 32; off >= 1; off >>= 1) {
        v1 += __shfl_xor(v1, off, 64);
        v2 += __shfl_xor(v2, off, 64);
    }
    if (c == 0) {
        Wh1[r] = v1;
        unsigned int lo = f2bf(__expf(v2));
        unsigned int hi = f2bf(__expf(ALPHA * v2));
        BP[r] = lo | (hi << 16);
    }
}

// Kernel 2: R9 structure + spill-free consume-then-reload adj pipeline.
// Half-buffers G0/G1 (4 int4 each) are reloaded for phase ph+1 right after
// being consumed in phase ph; vmcnt(8) at phase end retires only the STAGE
// ops, so 8 adj loads stay in flight across the barrier (~1/2 phase of hiding).
__launch_bounds__(512, 4)
__global__ void attn_kernel(const int* __restrict__ adj,
                            const float* __restrict__ Wh1,
                            const unsigned short* __restrict__ WhbT,
                            const unsigned int* __restrict__ BPg,
                            float* __restrict__ accS, float* __restrict__ sS) {
    __shared__ unsigned short Bpanel[2][64 * JPH];   // 2 x 16 KB
    __shared__ unsigned int ldsBP[JB];               // 4 KB
    const int tid = threadIdx.x;
    const int w = tid >> 6;
    const int l = tid & 63;
    const int il = l & 15;
    const int ks = l >> 4;
    const int g = blockIdx.x >> 3;
    const int q = blockIdx.x & 7;      // j-group == XCD (round-robin)
    const int rowbase = g * RB + w * 16;
    const int i = rowbase + il;
    const int jbase = q * JB;

    const float wh1 = Wh1[i];
    const float A1 = __expf(wh1);
    const float A2 = __expf(ALPHA * wh1);

    // stage BP slice for this block's j-range (once)
    for (int idx = tid; idx < JB; idx += 512) ldsBP[idx] = BPg[jbase + idx];

#define STAGE(ph) { \
    unsigned short* dst0 = &Bpanel[(ph) & 1][w * 1024]; \
    _Pragma("unroll") \
    for (int k = 0; k < 2; ++k) { \
        int c = w * 8 + k * 4 + (l >> 4); \
        int jl = ((l & 15) * 8) ^ ((c & 7) * 8); \
        const unsigned short* src = WhbT + (size_t)c * NN + jbase + (ph) * JPH + jl; \
        __builtin_amdgcn_global_load_lds((ga_cv*)src, (lds_v*)(dst0 + k * 512), 16, 0, 0); \
    } }

// load one 64-j half (4 dwordx4) of phase ph into dst[0..3]
#define ADJHALF(dst, ph, HALF) { \
    _Pragma("unroll") \
    for (int k = 0; k < 2; ++k) { \
        const int jo = (ph) * JPH + (2 * (HALF) + k) * 32 + ks * 8; \
        dst[2 * k]     = *reinterpret_cast<const i32x4*>(adj + adjRow + jbase + jo); \
        dst[2 * k + 1] = *reinterpret_cast<const i32x4*>(adj + adjRow + jbase + jo + 4); \
    } }

// compute one 64-j half (ks8 = 2*HALF .. 2*HALF+1) of phase ph from CUR[0..3]
#define COMPUTE_HALF(ph, HALF, CUR) { \
    _Pragma("unroll") \
    for (int kk2 = 0; kk2 < 2; ++kk2) { \
        const int ks8 = 2 * (HALF) + kk2; \
        const int jo = (ph) * JPH + ks8 * 32 + ks * 8; \
        i32x4 p0 = *reinterpret_cast<const i32x4*>(&ldsBP[jo]); \
        i32x4 p1 = *reinterpret_cast<const i32x4*>(&ldsBP[jo + 4]); \
        int pv[8] = {p0.x, p0.y, p0.z, p0.w, p1.x, p1.y, p1.z, p1.w}; \
        int av[8] = {CUR[2 * kk2].x, CUR[2 * kk2].y, CUR[2 * kk2].z, CUR[2 * kk2].w, \
                     CUR[2 * kk2 + 1].x, CUR[2 * kk2 + 1].y, CUR[2 * kk2 + 1].z, CUR[2 * kk2 + 1].w}; \
        s16x8 afrag; \
        _Pragma("unroll") \
        for (int b = 0; b < 8; ++b) { \
            unsigned int u = (unsigned int)pv[b]; \
            float b1 = bits2f(u << 16); \
            float b2 = bits2f(u & 0xffff0000u); \
            float pf = fmaxf(A1 * b1, A2 * b2); \
            pf = av[b] ? pf : 0.f; \
            afrag[b] = (short)f2bf(pf); \
        } \
        acc_s = __builtin_amdgcn_mfma_f32_16x16x32_bf16(afrag, ones, acc_s, 0, 0, 0); \
        const int off_e = (ks8 * 32 + ks * 8) ^ swzmask; \
        _Pragma("unroll") \
        for (int ct = 0; ct < 4; ++ct) { \
            s16x8 bfrag = *reinterpret_cast<const s16x8*>( \
                &Bpanel[(ph) & 1][(ct * 16 + il) * JPH + off_e]); \
            acc[ct] = __builtin_amdgcn_mfma_f32_16x16x32_bf16(afrag, bfrag, acc[ct], 0, 0, 0); \
        } \
    } }

#define VMW(n) { asm volatile("s_waitcnt vmcnt(" #n ")" ::: "memory"); \
                 __builtin_amdgcn_sched_barrier(0); }

    f32x4 acc[4] = {{0,0,0,0},{0,0,0,0},{0,0,0,0},{0,0,0,0}};
    f32x4 acc_s = {0,0,0,0};
    s16x8 ones;
#pragma unroll
    for (int b = 0; b < 8; ++b) ones[b] = (short)0x3F80;  // bf16 1.0

    const size_t adjRow = (size_t)i * NN;
    const int swzmask = (il & 7) * 8;

    i32x4 G0[4], G1[4];

    // prologue: ldsBP fill + STAGE(0) retired; G0(0),G1(0) left in flight
    STAGE(0);
    __builtin_amdgcn_sched_barrier(0);
    ADJHALF(G0, 0, 0);
    ADJHALF(G1, 0, 1);
    __builtin_amdgcn_sched_barrier(0);
    asm volatile("s_waitcnt vmcnt(8) lgkmcnt(0)" ::: "memory");
    __builtin_amdgcn_s_barrier();
    __builtin_amdgcn_sched_barrier(0);

    // invariant at each phase entry: outstanding = [G0(ph) 4, G1(ph) 4]
    for (int ph = 0; ph < NPH - 1; ++ph) {
        STAGE(ph + 1);                     // -> [G0 4, G1 4, ST 2]
        __builtin_amdgcn_sched_barrier(0);
        VMW(6);                            // retire G0(ph)
        COMPUTE_HALF(ph, 0, G0);
        __builtin_amdgcn_sched_barrier(0);
        ADJHALF(G0, ph + 1, 0);            // -> [G1 4, ST 2, G0' 4]
        __builtin_amdgcn_sched_barrier(0);
        VMW(6);                            // retire G1(ph)
        COMPUTE_HALF(ph, 1, G1);
        __builtin_amdgcn_sched_barrier(0);
        ADJHALF(G1, ph + 1, 1);            // -> [ST 2, G0' 4, G1' 4]
        __builtin_amdgcn_sched_barrier(0);
        VMW(8);                            // retire ST; G0',G1' fly across barrier
        __builtin_amdgcn_s_barrier();
        __builtin_amdgcn_sched_barrier(0);
    }
    // peeled last phase: no STAGE, no prefetch
    VMW(4);
    COMPUTE_HALF(NPH - 1, 0, G0);
    VMW(0);
    COMPUTE_HALF(NPH - 1, 1, G1);

    // sliced stores: every (q,row,col) written exactly once (no atomics, no zeroing)
#pragma unroll
    for (int ct = 0; ct < 4; ++ct)
#pragma unroll
        for (int r = 0; r < 4; ++r)
            accS[((size_t)q * NN + rowbase + ks * 4 + r) * OUTF + ct * 16 + il] = acc[ct][r];
    if (il == 0) {
#pragma unroll
        for (int r = 0; r < 4; ++r)
            sS[q * NN + rowbase + ks * 4 + r] = acc_s[r];
    }
}

__global__ void finalize_kernel(const float* __restrict__ accS, const float* __restrict__ sS,
                                float* __restrict__ out) {
    int t4 = blockIdx.x * blockDim.x + threadIdx.x;
    if (t4 >= NN * OUTF / 4) return;
    int row = t4 >> 4;
    float ss = 0.f;
    float4 v = {0.f, 0.f, 0.f, 0.f};
#pragma unroll
    for (int qq = 0; qq < 8; ++qq) {
        ss += sS[qq * NN + row];
        float4 p = reinterpret_cast<const float4*>(accS)[(size_t)qq * (NN * OUTF / 4) + t4];
        v.x += p.x; v.y += p.y; v.z += p.z; v.w += p.w;
    }
    float inv = (ss > 0.f) ? 1.f / ss : 0.f;
    float r[4] = {v.x * inv, v.y * inv, v.z * inv, v.w * inv};
#pragma unroll
    for (int k = 0; k < 4; ++k) r[k] = (r[k] > 0.f) ? r[k] : (__expf(r[k]) - 1.f);
    reinterpret_cast<float4*>(out)[t4] = float4{r[0], r[1], r[2], r[3]};
}

extern "C" void kernel_launch(void* const* d_in, const int* in_sizes, int n_in,
                              void* d_out, int out_size, void* d_ws, size_t ws_size,
                              hipStream_t stream) {
    const float* h   = (const float*)d_in[0];
    const int*   adj = (const int*)d_in[1];
    const float* W   = (const float*)d_in[2];
    const float* a   = (const float*)d_in[3];
    float* out = (float*)d_out;

    char* ws = (char*)d_ws;
    float* Wh1        = (float*)(ws);                            // 32 KB
    unsigned int* BP  = (unsigned int*)(ws + 32 * 1024);         // 32 KB
    unsigned short* WhbT = (unsigned short*)(ws + 64 * 1024);    // 1 MB
    float* accS = (float*)(ws + 2 * 1024 * 1024);                // 8 x 2 MB = 16 MB
    float* sS   = (float*)(ws + 18 * 1024 * 1024);               // 8 x 32 KB

    hipLaunchKernelGGL(prep_kernel, dim3(NN / 4), dim3(256), 0, stream,
                       h, W, a, Wh1, WhbT, BP);
    hipLaunchKernelGGL(attn_kernel, dim3((NN / RB) * (NN / JB)), dim3(512), 0, stream,
                       adj, Wh1, WhbT, BP, accS, sS);
    hipLaunchKernelGGL(finalize_kernel, dim3(NN * OUTF / 4 / 256), dim3(256), 0, stream,
                       accS, sS, out);
}

// Round 18
// 72.734 us; speedup vs baseline: 4.5052x; 1.0502x over previous
//
#include <hip/hip_runtime.h>
#include <hip/hip_bf16.h>
#include <stdint.h>

#define NN 8192
#define INF 128
#define OUTF 64
#define ALPHA 0.2f
#define RB 128      // rows per attn block
#define JB 1024     // j-range per attn block
#define JPH 128     // j per staged phase
#define NPH (JB / JPH)

typedef __attribute__((ext_vector_type(8))) short s16x8;
typedef __attribute__((ext_vector_type(4))) float f32x4;
typedef __attribute__((ext_vector_type(4))) int i32x4;

typedef __attribute__((address_space(1))) const void ga_cv;
typedef __attribute__((address_space(3))) void lds_v;

__device__ __forceinline__ unsigned short f2bf(float f) {
    union { float f; unsigned int u; } v; v.f = f;
    return (unsigned short)((v.u + 0x8000u) >> 16);   // round-half-up (validated R4-R17)
}
__device__ __forceinline__ unsigned short f2bf_rne(float f) {
    union { float f; unsigned int u; } v; v.f = f;
    unsigned int r = v.u + 0x7fffu + ((v.u >> 16) & 1u);
    return (unsigned short)(r >> 16);
}
__device__ __forceinline__ float bits2f(unsigned int u) {
    union { unsigned int u; float f; } v; v.u = u;
    return v.f;
}

// Kernel 1: Wh = h@W -> Wh1 (f32), WhbT (bf16 [64][8192]),
// BP[j] = pack(bf16(e^Wh2_j), bf16(e^{0.2 Wh2_j}))
__global__ void prep_kernel(const float* __restrict__ h, const float* __restrict__ W,
                            const float* __restrict__ a,
                            float* __restrict__ Wh1,
                            unsigned short* __restrict__ WhbT,
                            unsigned int* __restrict__ BP) {
    __shared__ float ldsW[INF * OUTF];
    int t = threadIdx.x;
    for (int idx = t; idx < INF * OUTF; idx += 256) ldsW[idx] = W[idx];
    __syncthreads();
    int r = blockIdx.x * 4 + (t >> 6);
    int c = t & 63;
    const float4* h4 = reinterpret_cast<const float4*>(h + (size_t)r * INF);
    float dot = 0.f;
#pragma unroll
    for (int kk = 0; kk < INF / 4; ++kk) {
        float4 hv = h4[kk];
        dot += hv.x * ldsW[(4 * kk + 0) * OUTF + c];
        dot += hv.y * ldsW[(4 * kk + 1) * OUTF + c];
        dot += hv.z * ldsW[(4 * kk + 2) * OUTF + c];
        dot += hv.w * ldsW[(4 * kk + 3) * OUTF + c];
    }
    WhbT[(size_t)c * NN + r] = f2bf_rne(dot);
    float v1 = dot * a[c];
    float v2 = dot * a[OUTF + c];
#pragma unroll
    for (int off = 32; off >= 1; off >>= 1) {
        v1 += __shfl_xor(v1, off, 64);
        v2 += __shfl_xor(v2, off, 64);
    }
    if (c == 0) {
        Wh1[r] = v1;
        unsigned int lo = f2bf(__expf(v2));
        unsigned int hi = f2bf(__expf(ALPHA * v2));
        BP[r] = lo | (hi << 16);
    }
}

// Kernel 2: R13 pipeline; epilogue routes acc through LDS (Bpanel reuse) and
// stores bf16-packed slices (8 MB total vs 16), fully coalesced dwordx4.
__launch_bounds__(512, 4)
__global__ void attn_kernel(const int* __restrict__ adj,
                            const float* __restrict__ Wh1,
                            const unsigned short* __restrict__ WhbT,
                            const unsigned int* __restrict__ BPg,
                            unsigned short* __restrict__ accB, float* __restrict__ sS) {
    __shared__ unsigned short Bpanel[2][64 * JPH];   // 2 x 16 KB (scratch later)
    __shared__ unsigned int ldsBP[JB];               // 4 KB
    const int tid = threadIdx.x;
    const int w = tid >> 6;
    const int l = tid & 63;
    const int il = l & 15;
    const int ks = l >> 4;
    const int g = blockIdx.x >> 3;
    const int q = blockIdx.x & 7;      // j-group == XCD (round-robin)
    const int rowbase = g * RB + w * 16;
    const int i = rowbase + il;
    const int jbase = q * JB;

    const float wh1 = Wh1[i];
    const float A1 = __expf(wh1);
    const float A2 = __expf(ALPHA * wh1);

    // stage BP slice for this block's j-range (once)
    for (int idx = tid; idx < JB; idx += 512) ldsBP[idx] = BPg[jbase + idx];

#define STAGE(ph) { \
    unsigned short* dst0 = &Bpanel[(ph) & 1][w * 1024]; \
    _Pragma("unroll") \
    for (int k = 0; k < 2; ++k) { \
        int c = w * 8 + k * 4 + (l >> 4); \
        int jl = ((l & 15) * 8) ^ ((c & 7) * 8); \
        const unsigned short* src = WhbT + (size_t)c * NN + jbase + (ph) * JPH + jl; \
        __builtin_amdgcn_global_load_lds((ga_cv*)src, (lds_v*)(dst0 + k * 512), 16, 0, 0); \
    } }

#define ADJHALF(dst, ph, HALF) { \
    _Pragma("unroll") \
    for (int k = 0; k < 2; ++k) { \
        const int jo = (ph) * JPH + (2 * (HALF) + k) * 32 + ks * 8; \
        dst[2 * k]     = *reinterpret_cast<const i32x4*>(adj + adjRow + jbase + jo); \
        dst[2 * k + 1] = *reinterpret_cast<const i32x4*>(adj + adjRow + jbase + jo + 4); \
    } }

#define COMPUTE_HALF(ph, HALF, CUR) { \
    _Pragma("unroll") \
    for (int kk2 = 0; kk2 < 2; ++kk2) { \
        const int ks8 = 2 * (HALF) + kk2; \
        const int jo = (ph) * JPH + ks8 * 32 + ks * 8; \
        i32x4 p0 = *reinterpret_cast<const i32x4*>(&ldsBP[jo]); \
        i32x4 p1 = *reinterpret_cast<const i32x4*>(&ldsBP[jo + 4]); \
        int pv[8] = {p0.x, p0.y, p0.z, p0.w, p1.x, p1.y, p1.z, p1.w}; \
        int av[8] = {CUR[2 * kk2].x, CUR[2 * kk2].y, CUR[2 * kk2].z, CUR[2 * kk2].w, \
                     CUR[2 * kk2 + 1].x, CUR[2 * kk2 + 1].y, CUR[2 * kk2 + 1].z, CUR[2 * kk2 + 1].w}; \
        s16x8 afrag; \
        _Pragma("unroll") \
        for (int b = 0; b < 8; ++b) { \
            unsigned int u = (unsigned int)pv[b]; \
            float b1 = bits2f(u << 16); \
            float b2 = bits2f(u & 0xffff0000u); \
            float pf = fmaxf(A1 * b1, A2 * b2); \
            pf = av[b] ? pf : 0.f; \
            afrag[b] = (short)f2bf(pf); \
        } \
        acc_s = __builtin_amdgcn_mfma_f32_16x16x32_bf16(afrag, ones, acc_s, 0, 0, 0); \
        const int off_e = (ks8 * 32 + ks * 8) ^ swzmask; \
        _Pragma("unroll") \
        for (int ct = 0; ct < 4; ++ct) { \
            s16x8 bfrag = *reinterpret_cast<const s16x8*>( \
                &Bpanel[(ph) & 1][(ct * 16 + il) * JPH + off_e]); \
            acc[ct] = __builtin_amdgcn_mfma_f32_16x16x32_bf16(afrag, bfrag, acc[ct], 0, 0, 0); \
        } \
    } }

#define VMW(n) { asm volatile("s_waitcnt vmcnt(" #n ")" ::: "memory"); \
                 __builtin_amdgcn_sched_barrier(0); }

    f32x4 acc[4] = {{0,0,0,0},{0,0,0,0},{0,0,0,0},{0,0,0,0}};
    f32x4 acc_s = {0,0,0,0};
    s16x8 ones;
#pragma unroll
    for (int b = 0; b < 8; ++b) ones[b] = (short)0x3F80;  // bf16 1.0

    const size_t adjRow = (size_t)i * NN;
    const int swzmask = (il & 7) * 8;

    i32x4 G0[4], G1[4];

    // prologue: ldsBP fill + STAGE(0) retired; G0(0),G1(0) left in flight
    STAGE(0);
    __builtin_amdgcn_sched_barrier(0);
    ADJHALF(G0, 0, 0);
    ADJHALF(G1, 0, 1);
    __builtin_amdgcn_sched_barrier(0);
    asm volatile("s_waitcnt vmcnt(8) lgkmcnt(0)" ::: "memory");
    __builtin_amdgcn_s_barrier();
    __builtin_amdgcn_sched_barrier(0);

    // invariant at each phase entry: outstanding = [G0(ph) 4, G1(ph) 4]
    for (int ph = 0; ph < NPH - 1; ++ph) {
        STAGE(ph + 1);                     // -> [G0 4, G1 4, ST 2]
        __builtin_amdgcn_sched_barrier(0);
        VMW(6);                            // retire G0(ph)
        COMPUTE_HALF(ph, 0, G0);
        __builtin_amdgcn_sched_barrier(0);
        ADJHALF(G0, ph + 1, 0);            // -> [G1 4, ST 2, G0' 4]
        __builtin_amdgcn_sched_barrier(0);
        VMW(6);                            // retire G1(ph)
        COMPUTE_HALF(ph, 1, G1);
        __builtin_amdgcn_sched_barrier(0);
        ADJHALF(G1, ph + 1, 1);            // -> [ST 2, G0' 4, G1' 4]
        __builtin_amdgcn_sched_barrier(0);
        VMW(8);                            // retire ST; G0',G1' fly across barrier
        __builtin_amdgcn_s_barrier();
        __builtin_amdgcn_sched_barrier(0);
    }
    // peeled last phase: no STAGE, no prefetch
    VMW(4);
    COMPUTE_HALF(NPH - 1, 0, G0);
    VMW(0);
    COMPUTE_HALF(NPH - 1, 1, G1);

    // epilogue: acc -> LDS scratch (Bpanel now dead) -> bf16-packed stores.
    // One writer per (q,row,col): bitwise deterministic.
    if (il == 0) {
#pragma unroll
        for (int r = 0; r < 4; ++r)
            sS[q * NN + rowbase + ks * 4 + r] = acc_s[r];
    }
    __syncthreads();                      // all waves done reading Bpanel
    float* scr = (float*)Bpanel;          // 8192 floats = 32 KB
#pragma unroll
    for (int ct = 0; ct < 4; ++ct)
#pragma unroll
        for (int r = 0; r < 4; ++r)
            scr[(w * 16 + ks * 4 + r) * OUTF + ct * 16 + il] = acc[ct][r];
    __syncthreads();
    unsigned short* oBase = accB + ((size_t)q * NN + g * RB) * OUTF;
#pragma unroll
    for (int it = 0; it < 2; ++it) {
        const int idx = it * 512 + tid;   // 0..1023: row=idx>>3, colgroup=idx&7
        const int row = idx >> 3, cg = idx & 7;
        const float* s = &scr[row * OUTF + cg * 8];
        i32x4 pk;
#pragma unroll
        for (int k = 0; k < 4; ++k)
            ((unsigned int*)&pk)[k] = (unsigned int)f2bf_rne(s[2 * k])
                                    | ((unsigned int)f2bf_rne(s[2 * k + 1]) << 16);
        *reinterpret_cast<i32x4*>(oBase + (size_t)row * OUTF + cg * 8) = pk;
    }
}

__global__ void finalize_kernel(const unsigned short* __restrict__ accB,
                                const float* __restrict__ sS,
                                float* __restrict__ out) {
    const int t8 = blockIdx.x * blockDim.x + threadIdx.x;   // 8-col group index
    if (t8 >= NN * OUTF / 8) return;
    const int row = t8 >> 3, cg = t8 & 7;
    float ss = 0.f;
    float v[8] = {0.f, 0.f, 0.f, 0.f, 0.f, 0.f, 0.f, 0.f};
#pragma unroll
    for (int qq = 0; qq < 8; ++qq) {      // FIXED order -> deterministic
        ss += sS[qq * NN + row];
        i32x4 pk = *reinterpret_cast<const i32x4*>(
            accB + ((size_t)qq * NN + row) * OUTF + cg * 8);
#pragma unroll
        for (int k = 0; k < 4; ++k) {
            unsigned int u = (unsigned int)((unsigned int*)&pk)[k];
            v[2 * k]     += bits2f(u << 16);
            v[2 * k + 1] += bits2f(u & 0xffff0000u);
        }
    }
    const float inv = (ss > 0.f) ? 1.f / ss : 0.f;
    float r[8];
#pragma unroll
    for (int k = 0; k < 8; ++k) {
        float qv = v[k] * inv;
        r[k] = (qv > 0.f) ? qv : (__expf(qv) - 1.f);
    }
    float4* o = reinterpret_cast<float4*>(out + (size_t)row * OUTF + cg * 8);
    o[0] = float4{r[0], r[1], r[2], r[3]};
    o[1] = float4{r[4], r[5], r[6], r[7]};
}

extern "C" void kernel_launch(void* const* d_in, const int* in_sizes, int n_in,
                              void* d_out, int out_size, void* d_ws, size_t ws_size,
                              hipStream_t stream) {
    const float* h   = (const float*)d_in[0];
    const int*   adj = (const int*)d_in[1];
    const float* W   = (const float*)d_in[2];
    const float* a   = (const float*)d_in[3];
    float* out = (float*)d_out;

    char* ws = (char*)d_ws;
    float* Wh1        = (float*)(ws);                            // 32 KB
    unsigned int* BP  = (unsigned int*)(ws + 32 * 1024);         // 32 KB
    unsigned short* WhbT = (unsigned short*)(ws + 64 * 1024);    // 1 MB
    unsigned short* accB = (unsigned short*)(ws + 2 * 1024 * 1024);  // 8 x 1 MB = 8 MB
    float* sS   = (float*)(ws + 10 * 1024 * 1024 + 512 * 1024);  // 8 x 32 KB

    hipLaunchKernelGGL(prep_kernel, dim3(NN / 4), dim3(256), 0, stream,
                       h, W, a, Wh1, WhbT, BP);
    hipLaunchKernelGGL(attn_kernel, dim3((NN / RB) * (NN / JB)), dim3(512), 0, stream,
                       adj, Wh1, WhbT, BP, accB, sS);
    hipLaunchKernelGGL(finalize_kernel, dim3(NN * OUTF / 8 / 256), dim3(256), 0, stream,
                       accB, sS, out);
}

// Round 19
// 71.691 us; speedup vs baseline: 4.5708x; 1.0146x over previous
//
#include <hip/hip_runtime.h>
#include <hip/hip_bf16.h>
#include <stdint.h>

#define NN 8192
#define INF 128
#define OUTF 64
#define ALPHA 0.2f
#define RB 128      // rows per attn block
#define JB 1024     // j-range per attn block
#define JPH 128     // j per staged phase
#define NPH (JB / JPH)

typedef __attribute__((ext_vector_type(8))) short s16x8;
typedef __attribute__((ext_vector_type(4))) float f32x4;
typedef __attribute__((ext_vector_type(4))) int i32x4;

typedef __attribute__((address_space(1))) const void ga_cv;
typedef __attribute__((address_space(3))) void lds_v;

__device__ __forceinline__ unsigned short f2bf(float f) {
    union { float f; unsigned int u; } v; v.f = f;
    return (unsigned short)((v.u + 0x8000u) >> 16);   // round-half-up (validated R4-R18)
}
__device__ __forceinline__ unsigned short f2bf_rne(float f) {
    union { float f; unsigned int u; } v; v.f = f;
    unsigned int r = v.u + 0x7fffu + ((v.u >> 16) & 1u);
    return (unsigned short)(r >> 16);
}
__device__ __forceinline__ float bits2f(unsigned int u) {
    union { unsigned int u; float f; } v; v.u = u;
    return v.f;
}

// Kernel 1: Wh = h@W -> Wh1 (f32), WhbT (bf16 [64][8192]),
// BP[j] = pack(bf16(e^Wh2_j), bf16(e^{0.2 Wh2_j})). 512 blocks x 16 rows.
__global__ void prep_kernel(const float* __restrict__ h, const float* __restrict__ W,
                            const float* __restrict__ a,
                            float* __restrict__ Wh1,
                            unsigned short* __restrict__ WhbT,
                            unsigned int* __restrict__ BP) {
    __shared__ float ldsW[INF * OUTF];
    int t = threadIdx.x;
    for (int idx = t; idx < INF * OUTF; idx += 256) ldsW[idx] = W[idx];
    __syncthreads();
    int c = t & 63;
    const float a1 = a[c], a2 = a[OUTF + c];
#pragma unroll
    for (int rr = 0; rr < 4; ++rr) {
        int r = blockIdx.x * 16 + rr * 4 + (t >> 6);
        const float4* h4 = reinterpret_cast<const float4*>(h + (size_t)r * INF);
        float dot = 0.f;
#pragma unroll
        for (int kk = 0; kk < INF / 4; ++kk) {
            float4 hv = h4[kk];
            dot += hv.x * ldsW[(4 * kk + 0) * OUTF + c];
            dot += hv.y * ldsW[(4 * kk + 1) * OUTF + c];
            dot += hv.z * ldsW[(4 * kk + 2) * OUTF + c];
            dot += hv.w * ldsW[(4 * kk + 3) * OUTF + c];
        }
        WhbT[(size_t)c * NN + r] = f2bf_rne(dot);
        float v1 = dot * a1;
        float v2 = dot * a2;
#pragma unroll
        for (int off = 32; off >= 1; off >>= 1) {
            v1 += __shfl_xor(v1, off, 64);
            v2 += __shfl_xor(v2, off, 64);
        }
        if (c == 0) {
            Wh1[r] = v1;
            unsigned int lo = f2bf(__expf(v2));
            unsigned int hi = f2bf(__expf(ALPHA * v2));
            BP[r] = lo | (hi << 16);
        }
    }
}

// Kernel 2: R13 pipeline; R18 epilogue (LDS transpose + bf16-packed slices),
// NT stores for accB/sS (write-once data, keep out of L2).
__launch_bounds__(512, 4)
__global__ void attn_kernel(const int* __restrict__ adj,
                            const float* __restrict__ Wh1,
                            const unsigned short* __restrict__ WhbT,
                            const unsigned int* __restrict__ BPg,
                            unsigned short* __restrict__ accB, float* __restrict__ sS) {
    __shared__ unsigned short Bpanel[2][64 * JPH];   // 2 x 16 KB (scratch later)
    __shared__ unsigned int ldsBP[JB];               // 4 KB
    const int tid = threadIdx.x;
    const int w = tid >> 6;
    const int l = tid & 63;
    const int il = l & 15;
    const int ks = l >> 4;
    const int g = blockIdx.x >> 3;
    const int q = blockIdx.x & 7;      // j-group == XCD (round-robin)
    const int rowbase = g * RB + w * 16;
    const int i = rowbase + il;
    const int jbase = q * JB;

    const float wh1 = Wh1[i];
    const float A1 = __expf(wh1);
    const float A2 = __expf(ALPHA * wh1);

    // stage BP slice for this block's j-range (once)
    for (int idx = tid; idx < JB; idx += 512) ldsBP[idx] = BPg[jbase + idx];

#define STAGE(ph) { \
    unsigned short* dst0 = &Bpanel[(ph) & 1][w * 1024]; \
    _Pragma("unroll") \
    for (int k = 0; k < 2; ++k) { \
        int c = w * 8 + k * 4 + (l >> 4); \
        int jl = ((l & 15) * 8) ^ ((c & 7) * 8); \
        const unsigned short* src = WhbT + (size_t)c * NN + jbase + (ph) * JPH + jl; \
        __builtin_amdgcn_global_load_lds((ga_cv*)src, (lds_v*)(dst0 + k * 512), 16, 0, 0); \
    } }

#define ADJHALF(dst, ph, HALF) { \
    _Pragma("unroll") \
    for (int k = 0; k < 2; ++k) { \
        const int jo = (ph) * JPH + (2 * (HALF) + k) * 32 + ks * 8; \
        dst[2 * k]     = *reinterpret_cast<const i32x4*>(adj + adjRow + jbase + jo); \
        dst[2 * k + 1] = *reinterpret_cast<const i32x4*>(adj + adjRow + jbase + jo + 4); \
    } }

#define COMPUTE_HALF(ph, HALF, CUR) { \
    _Pragma("unroll") \
    for (int kk2 = 0; kk2 < 2; ++kk2) { \
        const int ks8 = 2 * (HALF) + kk2; \
        const int jo = (ph) * JPH + ks8 * 32 + ks * 8; \
        i32x4 p0 = *reinterpret_cast<const i32x4*>(&ldsBP[jo]); \
        i32x4 p1 = *reinterpret_cast<const i32x4*>(&ldsBP[jo + 4]); \
        int pv[8] = {p0.x, p0.y, p0.z, p0.w, p1.x, p1.y, p1.z, p1.w}; \
        int av[8] = {CUR[2 * kk2].x, CUR[2 * kk2].y, CUR[2 * kk2].z, CUR[2 * kk2].w, \
                     CUR[2 * kk2 + 1].x, CUR[2 * kk2 + 1].y, CUR[2 * kk2 + 1].z, CUR[2 * kk2 + 1].w}; \
        s16x8 afrag; \
        _Pragma("unroll") \
        for (int b = 0; b < 8; ++b) { \
            unsigned int u = (unsigned int)pv[b]; \
            float b1 = bits2f(u << 16); \
            float b2 = bits2f(u & 0xffff0000u); \
            float pf = fmaxf(A1 * b1, A2 * b2); \
            pf = av[b] ? pf : 0.f; \
            afrag[b] = (short)f2bf(pf); \
        } \
        acc_s = __builtin_amdgcn_mfma_f32_16x16x32_bf16(afrag, ones, acc_s, 0, 0, 0); \
        const int off_e = (ks8 * 32 + ks * 8) ^ swzmask; \
        _Pragma("unroll") \
        for (int ct = 0; ct < 4; ++ct) { \
            s16x8 bfrag = *reinterpret_cast<const s16x8*>( \
                &Bpanel[(ph) & 1][(ct * 16 + il) * JPH + off_e]); \
            acc[ct] = __builtin_amdgcn_mfma_f32_16x16x32_bf16(afrag, bfrag, acc[ct], 0, 0, 0); \
        } \
    } }

#define VMW(n) { asm volatile("s_waitcnt vmcnt(" #n ")" ::: "memory"); \
                 __builtin_amdgcn_sched_barrier(0); }

    f32x4 acc[4] = {{0,0,0,0},{0,0,0,0},{0,0,0,0},{0,0,0,0}};
    f32x4 acc_s = {0,0,0,0};
    s16x8 ones;
#pragma unroll
    for (int b = 0; b < 8; ++b) ones[b] = (short)0x3F80;  // bf16 1.0

    const size_t adjRow = (size_t)i * NN;
    const int swzmask = (il & 7) * 8;

    i32x4 G0[4], G1[4];

    // prologue: ldsBP fill + STAGE(0) retired; G0(0),G1(0) left in flight
    STAGE(0);
    __builtin_amdgcn_sched_barrier(0);
    ADJHALF(G0, 0, 0);
    ADJHALF(G1, 0, 1);
    __builtin_amdgcn_sched_barrier(0);
    asm volatile("s_waitcnt vmcnt(8) lgkmcnt(0)" ::: "memory");
    __builtin_amdgcn_s_barrier();
    __builtin_amdgcn_sched_barrier(0);

    // invariant at each phase entry: outstanding = [G0(ph) 4, G1(ph) 4]
    for (int ph = 0; ph < NPH - 1; ++ph) {
        STAGE(ph + 1);                     // -> [G0 4, G1 4, ST 2]
        __builtin_amdgcn_sched_barrier(0);
        VMW(6);                            // retire G0(ph)
        COMPUTE_HALF(ph, 0, G0);
        __builtin_amdgcn_sched_barrier(0);
        ADJHALF(G0, ph + 1, 0);            // -> [G1 4, ST 2, G0' 4]
        __builtin_amdgcn_sched_barrier(0);
        VMW(6);                            // retire G1(ph)
        COMPUTE_HALF(ph, 1, G1);
        __builtin_amdgcn_sched_barrier(0);
        ADJHALF(G1, ph + 1, 1);            // -> [ST 2, G0' 4, G1' 4]
        __builtin_amdgcn_sched_barrier(0);
        VMW(8);                            // retire ST; G0',G1' fly across barrier
        __builtin_amdgcn_s_barrier();
        __builtin_amdgcn_sched_barrier(0);
    }
    // peeled last phase: no STAGE, no prefetch
    VMW(4);
    COMPUTE_HALF(NPH - 1, 0, G0);
    VMW(0);
    COMPUTE_HALF(NPH - 1, 1, G1);

    // epilogue: acc -> LDS scratch (Bpanel dead) -> bf16-packed NT stores.
    if (il == 0) {
#pragma unroll
        for (int r = 0; r < 4; ++r)
            __builtin_nontemporal_store(acc_s[r], &sS[q * NN + rowbase + ks * 4 + r]);
    }
    __syncthreads();                      // all waves done reading Bpanel
    float* scr = (float*)Bpanel;          // 8192 floats = 32 KB
#pragma unroll
    for (int ct = 0; ct < 4; ++ct)
#pragma unroll
        for (int r = 0; r < 4; ++r)
            scr[(w * 16 + ks * 4 + r) * OUTF + ct * 16 + il] = acc[ct][r];
    __syncthreads();
    unsigned short* oBase = accB + ((size_t)q * NN + g * RB) * OUTF;
#pragma unroll
    for (int it = 0; it < 2; ++it) {
        const int idx = it * 512 + tid;   // 0..1023: row=idx>>3, colgroup=idx&7
        const int row = idx >> 3, cg = idx & 7;
        const float* s = &scr[row * OUTF + cg * 8];
        i32x4 pk;
#pragma unroll
        for (int k = 0; k < 4; ++k)
            ((unsigned int*)&pk)[k] = (unsigned int)f2bf_rne(s[2 * k])
                                    | ((unsigned int)f2bf_rne(s[2 * k + 1]) << 16);
        __builtin_nontemporal_store(pk,
            reinterpret_cast<i32x4*>(oBase + (size_t)row * OUTF + cg * 8));
    }
}

__global__ void finalize_kernel(const unsigned short* __restrict__ accB,
                                const float* __restrict__ sS,
                                float* __restrict__ out) {
    const int t8 = blockIdx.x * blockDim.x + threadIdx.x;   // 8-col group index
    if (t8 >= NN * OUTF / 8) return;
    const int row = t8 >> 3, cg = t8 & 7;
    float ss = 0.f;
    float v[8] = {0.f, 0.f, 0.f, 0.f, 0.f, 0.f, 0.f, 0.f};
#pragma unroll
    for (int qq = 0; qq < 8; ++qq) {      // FIXED order -> deterministic
        ss += sS[qq * NN + row];
        i32x4 pk = *reinterpret_cast<const i32x4*>(
            accB + ((size_t)qq * NN + row) * OUTF + cg * 8);
#pragma unroll
        for (int k = 0; k < 4; ++k) {
            unsigned int u = (unsigned int)((unsigned int*)&pk)[k];
            v[2 * k]     += bits2f(u << 16);
            v[2 * k + 1] += bits2f(u & 0xffff0000u);
        }
    }
    const float inv = (ss > 0.f) ? 1.f / ss : 0.f;
    float r[8];
#pragma unroll
    for (int k = 0; k < 8; ++k) {
        float qv = v[k] * inv;
        r[k] = (qv > 0.f) ? qv : (__expf(qv) - 1.f);
    }
    float4* o = reinterpret_cast<float4*>(out + (size_t)row * OUTF + cg * 8);
    o[0] = float4{r[0], r[1], r[2], r[3]};
    o[1] = float4{r[4], r[5], r[6], r[7]};
}

extern "C" void kernel_launch(void* const* d_in, const int* in_sizes, int n_in,
                              void* d_out, int out_size, void* d_ws, size_t ws_size,
                              hipStream_t stream) {
    const float* h   = (const float*)d_in[0];
    const int*   adj = (const int*)d_in[1];
    const float* W   = (const float*)d_in[2];
    const float* a   = (const float*)d_in[3];
    float* out = (float*)d_out;

    char* ws = (char*)d_ws;
    float* Wh1        = (float*)(ws);                            // 32 KB
    unsigned int* BP  = (unsigned int*)(ws + 32 * 1024);         // 32 KB
    unsigned short* WhbT = (unsigned short*)(ws + 64 * 1024);    // 1 MB
    unsigned short* accB = (unsigned short*)(ws + 2 * 1024 * 1024);  // 8 x 1 MB = 8 MB
    float* sS   = (float*)(ws + 10 * 1024 * 1024 + 512 * 1024);  // 8 x 32 KB

    hipLaunchKernelGGL(prep_kernel, dim3(NN / 16), dim3(256), 0, stream,
                       h, W, a, Wh1, WhbT, BP);
    hipLaunchKernelGGL(attn_kernel, dim3((NN / RB) * (NN / JB)), dim3(512), 0, stream,
                       adj, Wh1, WhbT, BP, accB, sS);
    hipLaunchKernelGGL(finalize_kernel, dim3(NN * OUTF / 8 / 256), dim3(256), 0, stream,
                       accB, sS, out);
}